// Round 6
// baseline (136.286 us; speedup 1.0000x reference)
//
#include <hip/hip_runtime.h>
#include <math.h>

#define B_  2
#define T_  2048
#define D_  512
#define H_  8
#define HD_ 64
#define QKVS (3*D_)   // 1536

typedef __bf16 bf16x8 __attribute__((ext_vector_type(8)));
typedef float  f32x4  __attribute__((ext_vector_type(4)));

__device__ inline unsigned short f2bf(float f) {   // RN-even fp32->bf16
  unsigned int u = __float_as_uint(f);
  return (unsigned short)((u + 0x7FFFu + ((u >> 16) & 1u)) >> 16);
}
__device__ inline unsigned int pack2bf(float lo, float hi) {
  return (unsigned int)f2bf(lo) | ((unsigned int)f2bf(hi) << 16);
}

// ---------------------------------------------------------------------------
// Fused cast fp32 -> bf16 for x, w_qkv, w_out in one launch (float4 units).
// ---------------------------------------------------------------------------
__global__ void cast_all(const float* __restrict__ x,
                         const float* __restrict__ wq,
                         const float* __restrict__ wo,
                         unsigned short* __restrict__ xb,
                         unsigned short* __restrict__ wqb,
                         unsigned short* __restrict__ wob) {
  const int n_x  = (B_ * T_ * D_) / 4;
  const int n_wq = (QKVS * D_) / 4;
  const int n_wo = (D_ * D_) / 4;
  int i = blockIdx.x * blockDim.x + threadIdx.x;
  const float* src; unsigned short* dst; int off;
  if (i < n_x)                    { src = x;  dst = xb;  off = i; }
  else if (i < n_x + n_wq)        { src = wq; dst = wqb; off = i - n_x; }
  else if (i < n_x + n_wq + n_wo) { src = wo; dst = wob; off = i - n_x - n_wq; }
  else return;
  float4 v = ((const float4*)src)[off];
  ushort4 o;
  o.x = f2bf(v.x); o.y = f2bf(v.y); o.z = f2bf(v.z); o.w = f2bf(v.w);
  ((ushort4*)dst)[off] = o;
}

// ---------------------------------------------------------------------------
// QKV GEMM (NT, 128x128, BK=32, 4 waves 2x2, 4x4 accs) with PERMUTED epilogue:
// each head's rows are written in residue-major position order
//   pos(t) = r*qd + min(r,md) + t/p,  r = t%p, qd = T/p, md = T%p
// into per-(b,h) planes Qr/Kr/Vr [bh][pos][64] (bf16).
// ---------------------------------------------------------------------------
__global__ __launch_bounds__(256)
void gemm_qkv(const unsigned short* __restrict__ A,
              const unsigned short* __restrict__ Bw,
              const float* __restrict__ bias,
              const int* __restrict__ periods,
              unsigned short* __restrict__ Qr,
              unsigned short* __restrict__ Kr,
              unsigned short* __restrict__ Vr,
              int M, int N, int K) {
  __shared__ short Asd[128 * 32];   // 8 KB
  __shared__ short Bsd[128 * 32];   // 8 KB

  const int tid = threadIdx.x;
  const int w   = tid >> 6;
  const int l   = tid & 63;
  const int wr  = w >> 1;
  const int wc  = w & 1;
  const int q   = l >> 4;
  const int ml  = l & 15;
  const int arow = l >> 2;
  const int kch  = (l & 3) * 8;

  const int rowbase = blockIdx.y * 128;
  const int colbase = blockIdx.x * 128;

  f32x4 acc[4][4] = {};

  for (int k0 = 0; k0 < K; k0 += 32) {
    __syncthreads();
    #pragma unroll
    for (int s = 0; s < 2; ++s) {
      const unsigned short* ga =
          A + (size_t)(rowbase + s * 64 + w * 16 + arow) * K + k0 + kch;
      __builtin_amdgcn_global_load_lds(
          (const __attribute__((address_space(1))) void*)ga,
          (__attribute__((address_space(3))) void*)&Asd[s * 2048 + w * 512],
          16, 0, 0);
      const unsigned short* gb =
          Bw + (size_t)(colbase + s * 64 + w * 16 + arow) * K + k0 + kch;
      __builtin_amdgcn_global_load_lds(
          (const __attribute__((address_space(1))) void*)gb,
          (__attribute__((address_space(3))) void*)&Bsd[s * 2048 + w * 512],
          16, 0, 0);
    }
    __syncthreads();

    bf16x8 af[4], bfr[4];
    #pragma unroll
    for (int mi = 0; mi < 4; ++mi)
      af[mi] = *(const bf16x8*)&Asd[(wr * 64 + mi * 16 + ml) * 32 + q * 8];
    #pragma unroll
    for (int ni = 0; ni < 4; ++ni)
      bfr[ni] = *(const bf16x8*)&Bsd[(wc * 64 + ni * 16 + ml) * 32 + q * 8];
    #pragma unroll
    for (int mi = 0; mi < 4; ++mi)
      #pragma unroll
      for (int ni = 0; ni < 4; ++ni)
        acc[mi][ni] = __builtin_amdgcn_mfma_f32_16x16x32_bf16(
            af[mi], bfr[ni], acc[mi][ni], 0, 0, 0);
  }

  // Permuted epilogue. This thread's 64-col block is within ONE head section.
  const int colb = colbase + wc * 64;           // 64-aligned
  const int sec  = colb >> 9;                   // 0=Q 1=K 2=V
  const int h    = (colb >> 6) & 7;
  const int bidx = rowbase >> 11;               // batch (blocks never straddle)
  unsigned short* plane =
      (sec == 0 ? Qr : (sec == 1 ? Kr : Vr)) +
      (size_t)(bidx * 8 + h) * (T_ * HD_);
  unsigned int pp = (unsigned int)periods[bidx * 8 + h];
  if ((int)pp < 1) pp = 1;
  const unsigned int qd = 2048u / pp;
  const unsigned int md = 2048u - qd * pp;

  #pragma unroll
  for (int mi = 0; mi < 4; ++mi) {
    #pragma unroll
    for (int r2 = 0; r2 < 4; ++r2) {
      const unsigned int t =
          (unsigned int)((rowbase + wr * 64 + mi * 16 + q * 4 + r2) & 2047);
      const unsigned int ti = t / pp;
      const unsigned int rr = t - ti * pp;
      const unsigned int pos = rr * qd + (rr < md ? rr : md) + ti;
      #pragma unroll
      for (int ni = 0; ni < 4; ++ni) {
        const int col = colb + ni * 16 + ml;
        plane[(size_t)pos * HD_ + ni * 16 + ml] =
            f2bf(acc[mi][ni][r2] + bias[col]);
      }
    }
  }
}

// ---------------------------------------------------------------------------
// V_r [bh][pos][64] -> VT_r [bh][64][2048] (pos-contiguous per d-row).
// Block = (bh, 128-pos chunk). LDS tile 128x64 (stride 72).
// ---------------------------------------------------------------------------
__global__ __launch_bounds__(256)
void transpose_v(const unsigned short* __restrict__ Vr,
                 unsigned short* __restrict__ VTr) {
  const int bh = blockIdx.x, chunk = blockIdx.y;
  const int pos0 = chunk * 128;
  __shared__ unsigned short Ls[128 * 72];
  const int tid = threadIdx.x;
  {
    const int row = tid >> 1, off = (tid & 1) * 32;
    const unsigned short* src = Vr + ((size_t)bh * T_ + pos0 + row) * HD_ + off;
    int4 v0 = ((const int4*)src)[0];
    int4 v1 = ((const int4*)src)[1];
    int4 v2 = ((const int4*)src)[2];
    int4 v3 = ((const int4*)src)[3];
    *(int4*)&Ls[row * 72 + off + 0]  = v0;
    *(int4*)&Ls[row * 72 + off + 8]  = v1;
    *(int4*)&Ls[row * 72 + off + 16] = v2;
    *(int4*)&Ls[row * 72 + off + 24] = v3;
  }
  __syncthreads();
  {
    const int d = tid >> 2, po = (tid & 3) * 32;
    unsigned int wv[16];
    #pragma unroll
    for (int i = 0; i < 16; ++i) {
      unsigned short lo = Ls[(po + 2 * i) * 72 + d];
      unsigned short hi = Ls[(po + 2 * i + 1) * 72 + d];
      wv[i] = (unsigned int)lo | ((unsigned int)hi << 16);
    }
    unsigned short* dst = VTr + ((size_t)bh * HD_ + d) * T_ + pos0 + po;
    ((int4*)dst)[0] = make_int4(wv[0],  wv[1],  wv[2],  wv[3]);
    ((int4*)dst)[1] = make_int4(wv[4],  wv[5],  wv[6],  wv[7]);
    ((int4*)dst)[2] = make_int4(wv[8],  wv[9],  wv[10], wv[11]);
    ((int4*)dst)[3] = make_int4(wv[12], wv[13], wv[14], wv[15]);
  }
}

// ---------------------------------------------------------------------------
// LDS-free, barrier-free residue-class flash attention.
// One wave per (bh, slot); slot -> (g = slot/p, r = slot%p); 16-query tile
// [g*16, g*16+16) of residue r. All MFMA fragments are direct 16B global
// loads from the pos-ordered planes (L2-resident). 64-key iterations.
// Max needed slot over p in [1,63] is 188 -> grid y = 192.
// ---------------------------------------------------------------------------
__global__ __launch_bounds__(64)
void attn_flash3(const unsigned short* __restrict__ Qr,
                 const unsigned short* __restrict__ Kr,
                 const unsigned short* __restrict__ VTr,
                 const int* __restrict__ periods,
                 unsigned short* __restrict__ ao) {
  const int bh = blockIdx.x, slot = blockIdx.y;
  int p = periods[bh]; if (p < 1) p = 1;
  const int g = slot / p;
  const int r = slot - g * p;
  const unsigned int qd = 2048u / (unsigned int)p;
  const unsigned int md = 2048u - qd * (unsigned int)p;
  const int L = (int)qd + (r < (int)md ? 1 : 0);
  const int q0 = g << 4;
  if (q0 >= L) return;
  const int off = r * (int)qd + min(r, (int)md);
  const int nq = min(16, L - q0);
  const int Nk = min(L, q0 + 16);

  const int lane = threadIdx.x;
  const int Q = lane >> 4, c = lane & 15;

  const unsigned short* Qp = Qr  + (size_t)bh * (T_ * HD_);
  const unsigned short* Kp = Kr  + (size_t)bh * (T_ * HD_);
  const unsigned short* Vp = VTr + (size_t)bh * (T_ * HD_);   // [d][2048]

  // Q B-frag: B[k=d=Q*8+j(+32h)][n=q=c]
  const int qpos = off + q0 + min(c, nq - 1);
  bf16x8 qf0 = *(const bf16x8*)(Qp + (size_t)qpos * HD_ + Q * 8);
  bf16x8 qf1 = *(const bf16x8*)(Qp + (size_t)qpos * HD_ + 32 + Q * 8);

  const int qglob = q0 + c;            // this lane's query t-index
  float m_run = -3.0e38f, l_run = 0.f;
  f32x4 o[4] = {};

  for (int k0 = 0; k0 < Nk; k0 += 64) {
    const int nt = min(4, (Nk - k0 + 15) >> 4);   // active 16-key tiles

    // ---- S^T tiles: A = K rows (direct global), B = qf ----
    float pvv[16];
    float tmax = -3.0e38f;
    #pragma unroll
    for (int mt = 0; mt < 4; ++mt) {
      if (mt < nt) {
        const int kpos = off + min(k0 + mt * 16 + c, Nk - 1);
        bf16x8 a0 = *(const bf16x8*)(Kp + (size_t)kpos * HD_ + Q * 8);
        bf16x8 a1 = *(const bf16x8*)(Kp + (size_t)kpos * HD_ + 32 + Q * 8);
        f32x4 s = {};
        s = __builtin_amdgcn_mfma_f32_16x16x32_bf16(a0, qf0, s, 0, 0, 0);
        s = __builtin_amdgcn_mfma_f32_16x16x32_bf16(a1, qf1, s, 0, 0, 0);
        #pragma unroll
        for (int rg = 0; rg < 4; ++rg) {
          const int kk = k0 + mt * 16 + Q * 4 + rg;
          float v = s[rg] * 0.125f;                // 1/sqrt(HD)
          v = (kk <= qglob) ? v : -3.0e38f;
          pvv[mt * 4 + rg] = v;
          tmax = fmaxf(tmax, v);
        }
      } else {
        #pragma unroll
        for (int rg = 0; rg < 4; ++rg) pvv[mt * 4 + rg] = -3.0e38f;
      }
    }

    // ---- online softmax per column (q = c) ----
    tmax = fmaxf(tmax, __shfl_xor(tmax, 16));
    tmax = fmaxf(tmax, __shfl_xor(tmax, 32));
    const float m_new = fmaxf(m_run, tmax);
    const float alpha = __expf(m_run - m_new);
    float tsum = 0.f;
    #pragma unroll
    for (int i = 0; i < 16; ++i) {
      pvv[i] = __expf(pvv[i] - m_new);
      tsum += pvv[i];
    }
    tsum += __shfl_xor(tsum, 16);
    tsum += __shfl_xor(tsum, 32);
    l_run = l_run * alpha + tsum;
    m_run = m_new;

    // ---- P^T -> B-operand frags per 32-key chunk (8 shfl + 4 sel each) ----
    bf16x8 pb[2];
    const int sq2 = (Q & 1) << 1;
    #pragma unroll
    for (int kc = 0; kc < 2; ++kc) {
      unsigned int pk0[2], pk1[2];
      pk0[0] = pack2bf(pvv[kc * 8 + 0], pvv[kc * 8 + 1]);
      pk0[1] = pack2bf(pvv[kc * 8 + 2], pvv[kc * 8 + 3]);
      pk1[0] = pack2bf(pvv[kc * 8 + 4], pvv[kc * 8 + 5]);
      pk1[1] = pack2bf(pvv[kc * 8 + 6], pvv[kc * 8 + 7]);
      int dw[4];
      #pragma unroll
      for (int d = 0; d < 4; ++d) {
        const int src = ((sq2 + (d >> 1)) << 4) + c;
        const int v0 = __shfl((int)pk0[d & 1], src);
        const int v1 = __shfl((int)pk1[d & 1], src);
        dw[d] = (Q >= 2) ? v1 : v0;
      }
      int4 bi = make_int4(dw[0], dw[1], dw[2], dw[3]);
      pb[kc] = *(bf16x8*)&bi;
    }

    // ---- O^T += V^T . P^T : A-frag = direct 16B load from VT plane ----
    #pragma unroll
    for (int ch = 0; ch < 4; ++ch) {
      #pragma unroll
      for (int t2 = 0; t2 < 4; ++t2) o[ch][t2] *= alpha;
    }
    #pragma unroll
    for (int kc = 0; kc < 2; ++kc) {
      if (k0 + kc * 32 < Nk) {
        #pragma unroll
        for (int ch = 0; ch < 4; ++ch) {
          bf16x8 af = *(const bf16x8*)(
              Vp + (size_t)(ch * 16 + c) * T_ + off + k0 + kc * 32 + Q * 8);
          o[ch] = __builtin_amdgcn_mfma_f32_16x16x32_bf16(af, pb[kc], o[ch],
                                                          0, 0, 0);
        }
      }
    }
  }

  // ---- epilogue: O[q][d] = O^T[d][q] / l, token = r + (q0+c)*p ----
  if (c < nq) {
    const float invl = 1.f / l_run;
    const int b = bh >> 3, h = bh & 7;
    const int tok = r + (q0 + c) * p;
    unsigned int* dst =
        (unsigned int*)(ao + (size_t)(b * T_ + tok) * D_ + h * HD_);
    #pragma unroll
    for (int ch = 0; ch < 4; ++ch)
      #pragma unroll
      for (int rp = 0; rp < 2; ++rp) {
        const int dhalf = ch * 16 + Q * 4 + rp * 2;   // even
        dst[dhalf >> 1] =
            pack2bf(o[ch][rp * 2] * invl, o[ch][rp * 2 + 1] * invl);
      }
  }
}

// ---------------------------------------------------------------------------
// Out-projection GEMM (NT, 128x64, BK=32) — unchanged from R5.
// ---------------------------------------------------------------------------
__global__ __launch_bounds__(256)
void gemm_out(const unsigned short* __restrict__ A,
              const unsigned short* __restrict__ Bw,
              const float* __restrict__ bias, float* __restrict__ C,
              int M, int N, int K) {
  __shared__ short Asd[128 * 32];
  __shared__ short Bsd[64 * 32];

  const int tid = threadIdx.x;
  const int w   = tid >> 6;
  const int l   = tid & 63;
  const int wr  = w >> 1;
  const int wc  = w & 1;
  const int q   = l >> 4;
  const int ml  = l & 15;
  const int arow = l >> 2;
  const int kch  = (l & 3) * 8;

  const int rowbase = blockIdx.y * 128;
  const int colbase = blockIdx.x * 64;

  f32x4 acc[4][2] = {};

  for (int k0 = 0; k0 < K; k0 += 32) {
    __syncthreads();
    #pragma unroll
    for (int s = 0; s < 2; ++s) {
      const unsigned short* ga =
          A + (size_t)(rowbase + s * 64 + w * 16 + arow) * K + k0 + kch;
      __builtin_amdgcn_global_load_lds(
          (const __attribute__((address_space(1))) void*)ga,
          (__attribute__((address_space(3))) void*)&Asd[s * 2048 + w * 512],
          16, 0, 0);
    }
    {
      const unsigned short* gb =
          Bw + (size_t)(colbase + w * 16 + arow) * K + k0 + kch;
      __builtin_amdgcn_global_load_lds(
          (const __attribute__((address_space(1))) void*)gb,
          (__attribute__((address_space(3))) void*)&Bsd[w * 512], 16, 0, 0);
    }
    __syncthreads();

    bf16x8 af[4], bfr[2];
    #pragma unroll
    for (int mi = 0; mi < 4; ++mi)
      af[mi] = *(const bf16x8*)&Asd[(wr * 64 + mi * 16 + ml) * 32 + q * 8];
    #pragma unroll
    for (int ni = 0; ni < 2; ++ni)
      bfr[ni] = *(const bf16x8*)&Bsd[(wc * 32 + ni * 16 + ml) * 32 + q * 8];
    #pragma unroll
    for (int mi = 0; mi < 4; ++mi)
      #pragma unroll
      for (int ni = 0; ni < 2; ++ni)
        acc[mi][ni] = __builtin_amdgcn_mfma_f32_16x16x32_bf16(
            af[mi], bfr[ni], acc[mi][ni], 0, 0, 0);
  }

  #pragma unroll
  for (int mi = 0; mi < 4; ++mi) {
    #pragma unroll
    for (int ni = 0; ni < 2; ++ni) {
      const int col = colbase + wc * 32 + ni * 16 + ml;
      const float bv = bias[col];
      #pragma unroll
      for (int r = 0; r < 4; ++r) {
        const int row = rowbase + wr * 64 + mi * 16 + q * 4 + r;
        C[(size_t)row * N + col] = acc[mi][ni][r] + bv;
      }
    }
  }
}

// ---------------------------------------------------------------------------
extern "C" void kernel_launch(void* const* d_in, const int* in_sizes, int n_in,
                              void* d_out, int out_size, void* d_ws, size_t ws_size,
                              hipStream_t stream) {
  const float* x      = (const float*)d_in[0];   // (B,T,D)
  const int*   period = (const int*)  d_in[1];   // (B,H)
  const float* w_qkv  = (const float*)d_in[2];   // (3D, D)
  const float* b_qkv  = (const float*)d_in[3];   // (3D,)
  const float* w_out  = (const float*)d_in[4];   // (D, D)
  const float* b_out  = (const float*)d_in[5];   // (D,)
  float* out = (float*)d_out;                    // (B,T,D)

  const int M = B_ * T_;                         // 4096

  // ws layout (MB): xb[0,4) wqb[4,5.5) wob[5.5,6)
  //                 Qr[6,10) Kr[10,14) Vr[14,18) VTr[18,22)+pad
  char* ws = (char*)d_ws;
  unsigned short* xb  = (unsigned short*)(ws);
  unsigned short* wqb = (unsigned short*)(ws + (size_t)M * D_ * 2);
  unsigned short* wob = (unsigned short*)(ws + (size_t)M * D_ * 2
                                             + (size_t)QKVS * D_ * 2);
  char* base6 = ws + (size_t)M * D_ * 2 + (size_t)QKVS * D_ * 2
                   + (size_t)D_ * D_ * 2;
  const size_t plane_bytes = (size_t)16 * T_ * HD_ * 2;   // 4 MB
  unsigned short* Qr  = (unsigned short*)(base6);
  unsigned short* Kr  = (unsigned short*)(base6 + plane_bytes);
  unsigned short* Vr  = (unsigned short*)(base6 + 2 * plane_bytes);
  unsigned short* VTr = (unsigned short*)(base6 + 3 * plane_bytes);
  unsigned short* aob = xb;   // alias: x_bf16 dead after GEMM1

  // fused input casts
  {
    const int n4 = (M * D_ + QKVS * D_ + D_ * D_) / 4;
    cast_all<<<dim3((n4 + 255) / 256), dim3(256), 0, stream>>>(
        x, w_qkv, w_out, xb, wqb, wob);
  }

  // 1) QKV projection -> pos-permuted bf16 planes Qr/Kr/Vr
  gemm_qkv<<<dim3(QKVS / 128, M / 128), dim3(256), 0, stream>>>(
      xb, wqb, b_qkv, period, Qr, Kr, Vr, M, QKVS, D_);

  // 1b) V_r -> VT_r (d-major, pos-contiguous)
  transpose_v<<<dim3(16, T_ / 128), dim3(256), 0, stream>>>(Vr, VTr);

  // 2) LDS-free flash attention -> aob (bf16, token-major)
  attn_flash3<<<dim3(16, 192), dim3(64), 0, stream>>>(
      Qr, Kr, VTr, period, aob);

  // 3) output projection -> fp32 out
  gemm_out<<<dim3(D_ / 64, M / 128), dim3(256), 0, stream>>>(
      aob, wob, b_out, out, M, D_, D_);
}

// Round 7
// 132.972 us; speedup vs baseline: 1.0249x; 1.0249x over previous
//
#include <hip/hip_runtime.h>
#include <math.h>

#define B_  2
#define T_  2048
#define D_  512
#define H_  8
#define HD_ 64
#define QKVS (3*D_)   // 1536

typedef __bf16 bf16x8 __attribute__((ext_vector_type(8)));
typedef float  f32x4  __attribute__((ext_vector_type(4)));

__device__ inline unsigned short f2bf(float f) {   // RN-even fp32->bf16
  unsigned int u = __float_as_uint(f);
  return (unsigned short)((u + 0x7FFFu + ((u >> 16) & 1u)) >> 16);
}
__device__ inline unsigned int pack2bf(float lo, float hi) {
  return (unsigned int)f2bf(lo) | ((unsigned int)f2bf(hi) << 16);
}

// ---------------------------------------------------------------------------
// Fused cast fp32 -> bf16 for x, w_qkv, w_out in one launch (float4 units).
// ---------------------------------------------------------------------------
__global__ void cast_all(const float* __restrict__ x,
                         const float* __restrict__ wq,
                         const float* __restrict__ wo,
                         unsigned short* __restrict__ xb,
                         unsigned short* __restrict__ wqb,
                         unsigned short* __restrict__ wob) {
  const int n_x  = (B_ * T_ * D_) / 4;
  const int n_wq = (QKVS * D_) / 4;
  const int n_wo = (D_ * D_) / 4;
  int i = blockIdx.x * blockDim.x + threadIdx.x;
  const float* src; unsigned short* dst; int off;
  if (i < n_x)                    { src = x;  dst = xb;  off = i; }
  else if (i < n_x + n_wq)        { src = wq; dst = wqb; off = i - n_x; }
  else if (i < n_x + n_wq + n_wo) { src = wo; dst = wob; off = i - n_x - n_wq; }
  else return;
  float4 v = ((const float4*)src)[off];
  ushort4 o;
  o.x = f2bf(v.x); o.y = f2bf(v.y); o.z = f2bf(v.z); o.w = f2bf(v.w);
  ((ushort4*)dst)[off] = o;
}

// ---------------------------------------------------------------------------
// MFMA bf16 GEMM (NT), 128x64 tile, BK=32: 4 waves, each 64x32 = 4x2 accs.
// BF16OUT=1 -> bf16 token-major C (qkv buffer); else fp32 C.
// grid 768 for N=1536 (3 blocks/CU), 256 for N=512 (1 block/CU).
// ---------------------------------------------------------------------------
template<int BF16OUT>
__global__ __launch_bounds__(256)
void gemm_nt_mfma(const unsigned short* __restrict__ A,
                  const unsigned short* __restrict__ Bw,
                  const float* __restrict__ bias, void* __restrict__ Cv,
                  int M, int N, int K) {
  __shared__ short Asd[128 * 32];
  __shared__ short Bsd[64 * 32];

  const int tid = threadIdx.x;
  const int w   = tid >> 6;
  const int l   = tid & 63;
  const int wr  = w >> 1;
  const int wc  = w & 1;
  const int q   = l >> 4;
  const int ml  = l & 15;
  const int arow = l >> 2;
  const int kch  = (l & 3) * 8;

  const int rowbase = blockIdx.y * 128;
  const int colbase = blockIdx.x * 64;

  f32x4 acc[4][2] = {};

  for (int k0 = 0; k0 < K; k0 += 32) {
    __syncthreads();
    #pragma unroll
    for (int s = 0; s < 2; ++s) {
      const unsigned short* g =
          A + (size_t)(rowbase + s * 64 + w * 16 + arow) * K + k0 + kch;
      __builtin_amdgcn_global_load_lds(
          (const __attribute__((address_space(1))) void*)g,
          (__attribute__((address_space(3))) void*)&Asd[s * 2048 + w * 512],
          16, 0, 0);
    }
    {
      const unsigned short* g =
          Bw + (size_t)(colbase + w * 16 + arow) * K + k0 + kch;
      __builtin_amdgcn_global_load_lds(
          (const __attribute__((address_space(1))) void*)g,
          (__attribute__((address_space(3))) void*)&Bsd[w * 512], 16, 0, 0);
    }
    __syncthreads();

    bf16x8 af[4], bfr[2];
    #pragma unroll
    for (int mi = 0; mi < 4; ++mi)
      af[mi] = *(const bf16x8*)&Asd[(wr * 64 + mi * 16 + ml) * 32 + q * 8];
    #pragma unroll
    for (int ni = 0; ni < 2; ++ni)
      bfr[ni] = *(const bf16x8*)&Bsd[(wc * 32 + ni * 16 + ml) * 32 + q * 8];
    #pragma unroll
    for (int mi = 0; mi < 4; ++mi)
      #pragma unroll
      for (int ni = 0; ni < 2; ++ni)
        acc[mi][ni] = __builtin_amdgcn_mfma_f32_16x16x32_bf16(
            af[mi], bfr[ni], acc[mi][ni], 0, 0, 0);
  }

  #pragma unroll
  for (int mi = 0; mi < 4; ++mi) {
    #pragma unroll
    for (int ni = 0; ni < 2; ++ni) {
      const int col = colbase + wc * 32 + ni * 16 + ml;
      const float bv = bias[col];
      #pragma unroll
      for (int r = 0; r < 4; ++r) {
        const int row = rowbase + wr * 64 + mi * 16 + q * 4 + r;
        const float val = acc[mi][ni][r] + bv;
        if (BF16OUT)
          ((unsigned short*)Cv)[(size_t)row * N + col] = f2bf(val);
        else
          ((float*)Cv)[(size_t)row * N + col] = val;
      }
    }
  }
}

// ---------------------------------------------------------------------------
// Gather-transpose: qkvb V-section (token-major) -> VT[bh][d][pos], where
// pos enumerates each residue class contiguously:
//   residues r < md have length qd+1, others qd (qd = T/p, md = T%p);
//   pos -> (r,t): thr = md*(qd+1);
//     pos <  thr: r = pos/(qd+1), t = pos - r*(qd+1)
//     pos >= thr: r = md + (pos-thr)/qd, t = (pos-thr)%qd
//   token = r + t*p.
// Block = (bh, 128-pos chunk). Reads gathered 128-B rows, writes coalesced.
// ---------------------------------------------------------------------------
__global__ __launch_bounds__(256)
void build_vt(const unsigned short* __restrict__ qkvb,
              const int* __restrict__ periods,
              unsigned short* __restrict__ VT) {
  const int bh = blockIdx.x, chunk = blockIdx.y;
  const int b = bh >> 3, h = bh & 7;
  int p = periods[bh]; if (p < 1) p = 1;
  const unsigned int qd = 2048u / (unsigned int)p;
  const unsigned int md = 2048u - qd * (unsigned int)p;
  const unsigned int thr = md * (qd + 1);
  const int pos0 = chunk * 128;

  __shared__ unsigned short Ls[128 * 72];
  const int tid = threadIdx.x;
  {
    const int row = tid >> 1, off = (tid & 1) * 32;
    const unsigned int pos = (unsigned int)(pos0 + row);
    unsigned int r, t;
    if (pos < thr) { r = pos / (qd + 1); t = pos - r * (qd + 1); }
    else { unsigned int e = pos - thr; r = md + e / qd; t = e - (e / qd) * qd; }
    const int token = (int)(r + t * (unsigned int)p);
    const unsigned short* src =
        qkvb + ((size_t)(b * T_ + token) * QKVS) + 2 * D_ + h * HD_ + off;
    int4 v0 = ((const int4*)src)[0];
    int4 v1 = ((const int4*)src)[1];
    int4 v2 = ((const int4*)src)[2];
    int4 v3 = ((const int4*)src)[3];
    *(int4*)&Ls[row * 72 + off + 0]  = v0;
    *(int4*)&Ls[row * 72 + off + 8]  = v1;
    *(int4*)&Ls[row * 72 + off + 16] = v2;
    *(int4*)&Ls[row * 72 + off + 24] = v3;
  }
  __syncthreads();
  {
    const int d = tid >> 2, po = (tid & 3) * 32;
    unsigned int wv[16];
    #pragma unroll
    for (int i = 0; i < 16; ++i) {
      unsigned short lo = Ls[(po + 2 * i) * 72 + d];
      unsigned short hi = Ls[(po + 2 * i + 1) * 72 + d];
      wv[i] = (unsigned int)lo | ((unsigned int)hi << 16);
    }
    unsigned short* dst = VT + ((size_t)bh * HD_ + d) * T_ + pos0 + po;
    ((int4*)dst)[0] = make_int4(wv[0],  wv[1],  wv[2],  wv[3]);
    ((int4*)dst)[1] = make_int4(wv[4],  wv[5],  wv[6],  wv[7]);
    ((int4*)dst)[2] = make_int4(wv[8],  wv[9],  wv[10], wv[11]);
    ((int4*)dst)[3] = make_int4(wv[12], wv[13], wv[14], wv[15]);
  }
}

// ---------------------------------------------------------------------------
// LDS-free, barrier-free residue-class flash attention.
// One wave per (bh, slot); slot -> (g = slot/p, r = slot%p); 16-query tile.
// Q/K fragments: direct 16B global loads from token-major qkvb at tokens
// r + idx*p (L2-resident). V^T fragments: direct 16B loads from VT plane
// (pos-contiguous). 64-key iterations, no LDS, no barriers.
// ---------------------------------------------------------------------------
__global__ __launch_bounds__(64)
void attn_flash3(const unsigned short* __restrict__ qkvb,
                 const unsigned short* __restrict__ VT,
                 const int* __restrict__ periods,
                 unsigned short* __restrict__ ao) {
  const int bh = blockIdx.x, slot = blockIdx.y;
  int p = periods[bh]; if (p < 1) p = 1;
  const int g = slot / p;
  const int r = slot - g * p;
  const unsigned int qd = 2048u / (unsigned int)p;
  const unsigned int md = 2048u - qd * (unsigned int)p;
  const int L = (int)qd + (r < (int)md ? 1 : 0);
  const int q0 = g << 4;
  if (q0 >= L) return;
  const int off = r * (int)qd + min(r, (int)md);   // pos base of residue r
  const int nq = min(16, L - q0);
  const int Nk = min(L, q0 + 16);

  const int lane = threadIdx.x;
  const int Q = lane >> 4, c = lane & 15;
  const int b = bh >> 3, h = bh & 7;

  const unsigned short* base = qkvb + (size_t)b * T_ * QKVS + h * HD_;
  const unsigned short* Vp   = VT + (size_t)bh * (T_ * HD_);   // [d][2048]

  // Q B-frag: B[k=d=Q*8+j(+32h)][n=q=c]
  const int qtok = r + (q0 + min(c, nq - 1)) * p;
  bf16x8 qf0 = *(const bf16x8*)(base + (size_t)qtok * QKVS + Q * 8);
  bf16x8 qf1 = *(const bf16x8*)(base + (size_t)qtok * QKVS + 32 + Q * 8);

  const int qglob = q0 + c;            // this lane's query t-index
  float m_run = -3.0e38f, l_run = 0.f;
  f32x4 o[4] = {};
  const unsigned short* Kb = base + D_;

  for (int k0 = 0; k0 < Nk; k0 += 64) {
    const int nt = min(4, (Nk - k0 + 15) >> 4);   // active 16-key tiles

    // ---- S^T tiles: A = K rows (direct global, token stride p), B = qf ----
    float pvv[16];
    float tmax = -3.0e38f;
    #pragma unroll
    for (int mt = 0; mt < 4; ++mt) {
      if (mt < nt) {
        const int ktok = r + min(k0 + mt * 16 + c, Nk - 1) * p;
        bf16x8 a0 = *(const bf16x8*)(Kb + (size_t)ktok * QKVS + Q * 8);
        bf16x8 a1 = *(const bf16x8*)(Kb + (size_t)ktok * QKVS + 32 + Q * 8);
        f32x4 s = {};
        s = __builtin_amdgcn_mfma_f32_16x16x32_bf16(a0, qf0, s, 0, 0, 0);
        s = __builtin_amdgcn_mfma_f32_16x16x32_bf16(a1, qf1, s, 0, 0, 0);
        #pragma unroll
        for (int rg = 0; rg < 4; ++rg) {
          const int kk = k0 + mt * 16 + Q * 4 + rg;
          float v = s[rg] * 0.125f;                // 1/sqrt(HD)
          v = (kk <= qglob) ? v : -3.0e38f;
          pvv[mt * 4 + rg] = v;
          tmax = fmaxf(tmax, v);
        }
      } else {
        #pragma unroll
        for (int rg = 0; rg < 4; ++rg) pvv[mt * 4 + rg] = -3.0e38f;
      }
    }

    // ---- online softmax per column (q = c) ----
    tmax = fmaxf(tmax, __shfl_xor(tmax, 16));
    tmax = fmaxf(tmax, __shfl_xor(tmax, 32));
    const float m_new = fmaxf(m_run, tmax);
    const float alpha = __expf(m_run - m_new);
    float tsum = 0.f;
    #pragma unroll
    for (int i = 0; i < 16; ++i) {
      pvv[i] = __expf(pvv[i] - m_new);
      tsum += pvv[i];
    }
    tsum += __shfl_xor(tsum, 16);
    tsum += __shfl_xor(tsum, 32);
    l_run = l_run * alpha + tsum;
    m_run = m_new;

    // ---- P^T -> B-operand frags per 32-key chunk (8 shfl + 4 sel each) ----
    bf16x8 pb[2];
    const int sq2 = (Q & 1) << 1;
    #pragma unroll
    for (int kc = 0; kc < 2; ++kc) {
      unsigned int pk0[2], pk1[2];
      pk0[0] = pack2bf(pvv[kc * 8 + 0], pvv[kc * 8 + 1]);
      pk0[1] = pack2bf(pvv[kc * 8 + 2], pvv[kc * 8 + 3]);
      pk1[0] = pack2bf(pvv[kc * 8 + 4], pvv[kc * 8 + 5]);
      pk1[1] = pack2bf(pvv[kc * 8 + 6], pvv[kc * 8 + 7]);
      int dw[4];
      #pragma unroll
      for (int d = 0; d < 4; ++d) {
        const int src = ((sq2 + (d >> 1)) << 4) + c;
        const int v0 = __shfl((int)pk0[d & 1], src);
        const int v1 = __shfl((int)pk1[d & 1], src);
        dw[d] = (Q >= 2) ? v1 : v0;
      }
      int4 bi = make_int4(dw[0], dw[1], dw[2], dw[3]);
      pb[kc] = *(bf16x8*)&bi;
    }

    // ---- O^T += V^T . P^T : A-frag = direct 16B load from VT plane ----
    #pragma unroll
    for (int ch = 0; ch < 4; ++ch) {
      #pragma unroll
      for (int t2 = 0; t2 < 4; ++t2) o[ch][t2] *= alpha;
    }
    #pragma unroll
    for (int kc = 0; kc < 2; ++kc) {
      if (k0 + kc * 32 < Nk) {
        #pragma unroll
        for (int ch = 0; ch < 4; ++ch) {
          bf16x8 af = *(const bf16x8*)(
              Vp + (size_t)(ch * 16 + c) * T_ + off + k0 + kc * 32 + Q * 8);
          o[ch] = __builtin_amdgcn_mfma_f32_16x16x32_bf16(af, pb[kc], o[ch],
                                                          0, 0, 0);
        }
      }
    }
  }

  // ---- epilogue: O[q][d] = O^T[d][q] / l, token = r + (q0+c)*p ----
  if (c < nq) {
    const float invl = 1.f / l_run;
    const int tok = r + (q0 + c) * p;
    unsigned int* dst =
        (unsigned int*)(ao + (size_t)(b * T_ + tok) * D_ + h * HD_);
    #pragma unroll
    for (int ch = 0; ch < 4; ++ch)
      #pragma unroll
      for (int rp = 0; rp < 2; ++rp) {
        const int dhalf = ch * 16 + Q * 4 + rp * 2;   // even
        dst[dhalf >> 1] =
            pack2bf(o[ch][rp * 2] * invl, o[ch][rp * 2 + 1] * invl);
      }
  }
}

// ---------------------------------------------------------------------------
extern "C" void kernel_launch(void* const* d_in, const int* in_sizes, int n_in,
                              void* d_out, int out_size, void* d_ws, size_t ws_size,
                              hipStream_t stream) {
  const float* x      = (const float*)d_in[0];   // (B,T,D)
  const int*   period = (const int*)  d_in[1];   // (B,H)
  const float* w_qkv  = (const float*)d_in[2];   // (3D, D)
  const float* b_qkv  = (const float*)d_in[3];   // (3D,)
  const float* w_out  = (const float*)d_in[4];   // (D, D)
  const float* b_out  = (const float*)d_in[5];   // (D,)
  float* out = (float*)d_out;                    // (B,T,D)

  const int M = B_ * T_;                         // 4096

  // ws layout (MB): xb[0,4) wqb[4,5.5) wob[5.5,6) qkvb[6,18) VT[18,22)
  char* ws = (char*)d_ws;
  unsigned short* xb   = (unsigned short*)(ws);
  unsigned short* wqb  = (unsigned short*)(ws + (size_t)M * D_ * 2);
  unsigned short* wob  = (unsigned short*)(ws + (size_t)M * D_ * 2
                                              + (size_t)QKVS * D_ * 2);
  unsigned short* qkvb = (unsigned short*)(ws + (size_t)M * D_ * 2
                                              + (size_t)QKVS * D_ * 2
                                              + (size_t)D_ * D_ * 2);
  unsigned short* VT   = (unsigned short*)((char*)qkvb + (size_t)M * QKVS * 2);
  unsigned short* aob  = xb;   // alias: x_bf16 dead after GEMM1

  // fused input casts
  {
    const int n4 = (M * D_ + QKVS * D_ + D_ * D_) / 4;
    cast_all<<<dim3((n4 + 255) / 256), dim3(256), 0, stream>>>(
        x, w_qkv, w_out, xb, wqb, wob);
  }

  // 1) QKV projection -> bf16 token-major qkvb (128x64 tile, grid 24x32=768)
  gemm_nt_mfma<1><<<dim3(QKVS / 64, M / 128), dim3(256), 0, stream>>>(
      xb, wqb, b_qkv, qkvb, M, QKVS, D_);

  // 1b) V -> VT[bh][d][pos] (pos-ordered, coalesced writes)
  build_vt<<<dim3(16, T_ / 128), dim3(256), 0, stream>>>(qkvb, period, VT);

  // 2) LDS-free flash attention -> aob (bf16, token-major)
  attn_flash3<<<dim3(16, 192), dim3(64), 0, stream>>>(
      qkvb, VT, period, aob);

  // 3) output projection -> fp32 out (128x64 tile, grid 8x32 = 256)
  gemm_nt_mfma<0><<<dim3(D_ / 64, M / 128), dim3(256), 0, stream>>>(
      aob, wob, b_out, out, M, D_, D_);
}